// Round 1
// baseline (1665.667 us; speedup 1.0000x reference)
//
#include <hip/hip_runtime.h>

// Problem constants
#define N_E    1024
#define E_DIM  512
#define BATCH  16
#define HW     4096                       // 64*64
#define NROW   (BATCH * HW)               // 65536 vectors
#define ZQ_SIZE (BATCH * E_DIM * HW)      // 8388608
#define LOSS_OFF ZQ_SIZE
#define IDX_OFF (ZQ_SIZE + 1)

// ws layout (bytes):
//   [0..8)        double loss accumulator
//   [64..4160)    cn[1024] code norms
//   [4160..2101312)   ct[512][1024] transposed codebook
//   [2101312..2363456) idx[65536] int
// total ~2.26 MB — well under typical ws_size.

// ---------------------------------------------------------------------------
// Kernel 1: codebook norms (wave per code) + zero loss accumulator
__global__ void k_prep_norms(const float* __restrict__ cb,
                             float* __restrict__ cn,
                             double* __restrict__ acc) {
    int lane = threadIdx.x & 63;
    int wid  = threadIdx.x >> 6;
    int j = blockIdx.x * 4 + wid;          // 256 blocks * 4 waves = 1024 codes
    const float* row = cb + (size_t)j * E_DIM;
    float s = 0.f;
    #pragma unroll
    for (int k = 0; k < E_DIM; k += 64) {
        float v = row[k + lane];
        s += v * v;
    }
    #pragma unroll
    for (int m = 32; m >= 1; m >>= 1) s += __shfl_xor(s, m);
    if (lane == 0) cn[j] = s;
    if (blockIdx.x == 0 && threadIdx.x == 0) *acc = 0.0;
}

// ---------------------------------------------------------------------------
// Kernel 2: codebook transpose cb[1024][512] -> ct[512][1024]
__global__ void k_transpose(const float* __restrict__ cb,
                            float* __restrict__ ct) {
    __shared__ float t[32][33];
    int tx = threadIdx.x & 31;
    int ty = threadIdx.x >> 5;             // 0..7
    int jt = blockIdx.x & 31;              // 32 j-tiles
    int ctl = blockIdx.x >> 5;             // 16 c-tiles
    int j0 = jt * 32, c0 = ctl * 32;
    #pragma unroll
    for (int i = 0; i < 4; i++) {
        int row = ty + i * 8;
        t[row][tx] = cb[(size_t)(j0 + row) * E_DIM + c0 + tx];
    }
    __syncthreads();
    #pragma unroll
    for (int i = 0; i < 4; i++) {
        int row = ty + i * 8;
        ct[(size_t)(c0 + row) * N_E + j0 + tx] = t[tx][row];
    }
}

// ---------------------------------------------------------------------------
// Kernel 3: distances + argmin.
// Block tile: 64 rows x 64 codes, K in chunks of 64, per-thread 4x4 micro-tile.
// z is [B, C, HW]; a 64-row tile == one contiguous 64-wide hw segment, so
// staging transposes z for free (coalesced float4 along w).
#define TR 64
#define TJ 64
#define TK 64
#define LDA 68   // pad: keeps 16B alignment for b128, breaks power-of-2 stride

__global__ __launch_bounds__(256) void k_argmin(
        const float* __restrict__ z,
        const float* __restrict__ cb,
        const float* __restrict__ cn,
        int* __restrict__ idxout) {
    __shared__ float at[TK][LDA];   // [c][row]
    __shared__ float bt[TK][LDA];   // [c][code]

    int tid = threadIdx.x;
    int tx = tid & 15;              // code group (4 codes)
    int ty = tid >> 4;              // row group (4 rows)
    int n0 = blockIdx.x * TR;
    int b   = n0 >> 12;             // n0 / 4096
    int hw0 = n0 & 4095;
    const float* zb = z + (size_t)b * E_DIM * HW + hw0;

    float bestv[4];
    int   besti[4];
    #pragma unroll
    for (int r = 0; r < 4; r++) { bestv[r] = 3.4e38f; besti[r] = 0; }

    for (int j0 = 0; j0 < N_E; j0 += TJ) {
        float acc[4][4];
        #pragma unroll
        for (int r = 0; r < 4; r++)
            #pragma unroll
            for (int jj = 0; jj < 4; jj++) acc[r][jj] = 0.f;

        for (int c0 = 0; c0 < E_DIM; c0 += TK) {
            __syncthreads();
            // stage A: z tile (transpose-on-load), coalesced float4 along w
            {
                int w  = (tid & 15) * 4;
                int cl = tid >> 4;
                #pragma unroll
                for (int i = 0; i < 4; i++, cl += 16) {
                    float4 v = *(const float4*)(zb + (size_t)(c0 + cl) * HW + w);
                    *(float4*)&at[cl][w] = v;
                }
            }
            // stage B: codebook tile, transposed into [c][code]
            {
                int coff = (tid & 15) * 4;
                int jl   = tid >> 4;
                #pragma unroll
                for (int i = 0; i < 4; i++, jl += 16) {
                    float4 v = *(const float4*)(cb + (size_t)(j0 + jl) * E_DIM + c0 + coff);
                    bt[coff + 0][jl] = v.x;
                    bt[coff + 1][jl] = v.y;
                    bt[coff + 2][jl] = v.z;
                    bt[coff + 3][jl] = v.w;
                }
            }
            __syncthreads();

            #pragma unroll 8
            for (int kk = 0; kk < TK; kk++) {
                float4 av = *(const float4*)&at[kk][ty * 4];
                float4 bv = *(const float4*)&bt[kk][tx * 4];
                acc[0][0] += av.x * bv.x; acc[0][1] += av.x * bv.y;
                acc[0][2] += av.x * bv.z; acc[0][3] += av.x * bv.w;
                acc[1][0] += av.y * bv.x; acc[1][1] += av.y * bv.y;
                acc[1][2] += av.y * bv.z; acc[1][3] += av.y * bv.w;
                acc[2][0] += av.z * bv.x; acc[2][1] += av.z * bv.y;
                acc[2][2] += av.z * bv.z; acc[2][3] += av.z * bv.w;
                acc[3][0] += av.w * bv.x; acc[3][1] += av.w * bv.y;
                acc[3][2] += av.w * bv.z; acc[3][3] += av.w * bv.w;
            }
        }

        // distances for this code chunk: d = ||e||^2 - 2 z.e  (row norm const)
        float cnv[4];
        #pragma unroll
        for (int jj = 0; jj < 4; jj++) cnv[jj] = cn[j0 + tx * 4 + jj];

        #pragma unroll
        for (int r = 0; r < 4; r++) {
            float v = cnv[0] - 2.f * acc[r][0];
            int   ix = j0 + tx * 4;
            #pragma unroll
            for (int jj = 1; jj < 4; jj++) {
                float d = cnv[jj] - 2.f * acc[r][jj];
                if (d < v) { v = d; ix = j0 + tx * 4 + jj; }   // ascending: < keeps first
            }
            // reduce across the 16 lanes sharing these rows
            #pragma unroll
            for (int m = 1; m <= 8; m <<= 1) {
                float ov = __shfl_xor(v, m);
                int   oi = __shfl_xor(ix, m);
                if (ov < v || (ov == v && oi < ix)) { v = ov; ix = oi; }
            }
            if (v < bestv[r] || (v == bestv[r] && ix < besti[r])) {
                bestv[r] = v; besti[r] = ix;
            }
        }
    }

    if (tx == 0) {
        #pragma unroll
        for (int r = 0; r < 4; r++) idxout[n0 + ty * 4 + r] = besti[r];
    }
}

// ---------------------------------------------------------------------------
// Kernel 4: gather z_q, straight-through output, loss partial sums, indices
__global__ void k_gather_loss(const float* __restrict__ z,
                              const float* __restrict__ ct,
                              const int* __restrict__ idx,
                              float* __restrict__ out,
                              double* __restrict__ acc) {
    int g = blockIdx.x * blockDim.x + threadIdx.x;   // float4 index, 0..2097151
    int w4 = g & 1023;
    int bc = g >> 10;
    int c  = bc & 511;
    int b  = bc >> 9;
    int n4 = b * 1024 + w4;                          // float4 index into idx space

    int4 iv = *(const int4*)(idx + (size_t)n4 * 4);
    const float* ctc = ct + (size_t)c * N_E;
    float4 zq;
    zq.x = ctc[iv.x]; zq.y = ctc[iv.y]; zq.z = ctc[iv.z]; zq.w = ctc[iv.w];
    float4 zv = *(const float4*)(z + (size_t)g * 4);

    float4 d;
    d.x = zq.x - zv.x; d.y = zq.y - zv.y; d.z = zq.z - zv.z; d.w = zq.w - zv.w;
    // straight-through: z_q_st = zp + (z_q - zp), matching ref order of ops
    float4 o;
    o.x = zv.x + d.x; o.y = zv.y + d.y; o.z = zv.z + d.z; o.w = zv.w + d.w;
    *(float4*)(out + (size_t)g * 4) = o;

    float ls = d.x * d.x + d.y * d.y + d.z * d.z + d.w * d.w;
    #pragma unroll
    for (int m = 32; m >= 1; m >>= 1) ls += __shfl_xor(ls, m);

    __shared__ float wsum[4];
    int lane = threadIdx.x & 63, wid = threadIdx.x >> 6;
    if (lane == 0) wsum[wid] = ls;
    __syncthreads();
    if (threadIdx.x == 0) {
        atomicAdd(acc, (double)(wsum[0] + wsum[1] + wsum[2] + wsum[3]));
    }

    if (c == 0) {
        // indices section starts at odd offset -> scalar stores
        float* ip = out + IDX_OFF + (size_t)n4 * 4;
        ip[0] = (float)iv.x; ip[1] = (float)iv.y;
        ip[2] = (float)iv.z; ip[3] = (float)iv.w;
    }
}

// ---------------------------------------------------------------------------
__global__ void k_final(const double* __restrict__ acc, float* __restrict__ out) {
    out[LOSS_OFF] = (float)(1.25 * (*acc) / (double)ZQ_SIZE);
}

// ---------------------------------------------------------------------------
extern "C" void kernel_launch(void* const* d_in, const int* in_sizes, int n_in,
                              void* d_out, int out_size, void* d_ws, size_t ws_size,
                              hipStream_t stream) {
    const float* z  = (const float*)d_in[0];
    const float* cb = (const float*)d_in[1];
    float* out = (float*)d_out;

    double* acc = (double*)d_ws;
    float* cn = (float*)d_ws + 16;          // byte offset 64
    float* ct = cn + 1024;                  // 512*1024 floats
    int*   idx = (int*)(ct + 512 * 1024);   // 65536 ints

    k_prep_norms<<<256, 256, 0, stream>>>(cb, cn, acc);
    k_transpose<<<512, 256, 0, stream>>>(cb, ct);
    k_argmin<<<NROW / TR, 256, 0, stream>>>(z, cb, cn, idx);
    k_gather_loss<<<ZQ_SIZE / 4 / 256, 256, 0, stream>>>(z, ct, idx, out, acc);
    k_final<<<1, 1, 0, stream>>>(acc, out);
}

// Round 3
// 615.027 us; speedup vs baseline: 2.7083x; 2.7083x over previous
//
#include <hip/hip_runtime.h>

// Problem constants
#define N_E    1024
#define E_DIM  512
#define BATCH  16
#define HW     4096                       // 64*64
#define NROW   (BATCH * HW)               // 65536 vectors
#define ZQ_SIZE (BATCH * E_DIM * HW)      // 8388608
#define LOSS_OFF ZQ_SIZE
#define IDX_OFF (ZQ_SIZE + 1)

typedef _Float16 half_t;
typedef __attribute__((ext_vector_type(2)))  __fp16   fp16x2;  // cvt_pkrtz native type
typedef __attribute__((ext_vector_type(8)))  _Float16 frag8;   // 4 VGPR MFMA operand
typedef __attribute__((ext_vector_type(16))) float    accv;    // 16 AGPR accumulator

union U32H2 { fp16x2 h; uint32_t u; };
union FragU { uint32_t u[4]; frag8 f; };

static __device__ inline uint32_t pack2(float a, float b) {
    U32H2 t; t.h = __builtin_amdgcn_cvt_pkrtz(a, b); return t.u;
}

// ---------------------------------------------------------------------------
// Kernel 1: codebook norms (wave per code), fp32
__global__ void k_prep_norms(const float* __restrict__ cb,
                             float* __restrict__ cn) {
    int lane = threadIdx.x & 63;
    int wid  = threadIdx.x >> 6;
    int j = blockIdx.x * 4 + wid;
    const float* row = cb + (size_t)j * E_DIM;
    float s = 0.f;
    #pragma unroll
    for (int k = 0; k < E_DIM; k += 64) {
        float v = row[k + lane];
        s += v * v;
    }
    #pragma unroll
    for (int m = 32; m >= 1; m >>= 1) s += __shfl_xor(s, m);
    if (lane == 0) cn[j] = s;
}

// ---------------------------------------------------------------------------
// Kernel 2: codebook transpose cb[1024][512] -> ct[512][1024] (for gather)
__global__ void k_transpose(const float* __restrict__ cb,
                            float* __restrict__ ct) {
    __shared__ float t[32][33];
    int tx = threadIdx.x & 31;
    int ty = threadIdx.x >> 5;
    int jt = blockIdx.x & 31;
    int ctl = blockIdx.x >> 5;
    int j0 = jt * 32, c0 = ctl * 32;
    #pragma unroll
    for (int i = 0; i < 4; i++) {
        int row = ty + i * 8;
        t[row][tx] = cb[(size_t)(j0 + row) * E_DIM + c0 + tx];
    }
    __syncthreads();
    #pragma unroll
    for (int i = 0; i < 4; i++) {
        int row = ty + i * 8;
        ct[(size_t)(c0 + row) * N_E + j0 + tx] = t[tx][row];
    }
}

// ---------------------------------------------------------------------------
// Kernel 3: MFMA distance argmin.
// f16-split: x = hi + lo (both f16); dot = hi*hi + hi*lo + lo*hi via 3 MFMAs
// (error ~1e-5, below fp32 GEMM rounding). Block: 256 thr = 4 waves (2x2),
// tile 128 rows x 128 codes per jt, jt loops over 8 code sub-tiles.
// A (z rows) packed (lo16|hi16) dwords in LDS stride 44; B hi/lo f16 stride 40.
#define ASTR 44   // dwords per A row (32 + pad; 176 B = 11*16 -> b128 aligned)
#define BSTR 40   // halves per B row (80 B = 5*16 -> b128 aligned)

__global__ __launch_bounds__(256, 2) void k_argmin_mfma(
        const float* __restrict__ z,
        const float* __restrict__ cb,
        const float* __restrict__ cn,
        int* __restrict__ idxout) {
    __shared__ uint32_t aP[128 * ASTR];
    __shared__ half_t   bH[128 * BSTR];
    __shared__ half_t   bL[128 * BSTR];
    __shared__ float    bwv[2][128];
    __shared__ int      bwi[2][128];

    int tid  = threadIdx.x;
    int lane = tid & 63;
    int l31  = lane & 31;
    int lh   = lane >> 5;
    int wm   = (tid >> 6) & 1;   // wave m-group (rows)
    int wg   = tid >> 7;         // wave n-group (codes)

    int n0  = blockIdx.x * 128;
    int b   = n0 >> 12;
    int hw0 = n0 & 4095;
    const float* zA = z + (size_t)b * E_DIM * HW + hw0 + 4 * (tid & 31);
    int a_kq = tid >> 5;                      // 0..7 (k quad for A staging)
    int b_kq = tid & 7;                       // k quad for B staging
    int b_j0 = tid >> 3;                      // 0..31

    if (tid < 128) {
        bwv[0][tid] = 3.4e38f; bwv[1][tid] = 3.4e38f;
        bwi[0][tid] = 0;       bwi[1][tid] = 0;
    }

    for (int jt = 0; jt < 8; jt++) {
        accv acc[2][2];
        #pragma unroll
        for (int mt = 0; mt < 2; mt++)
            #pragma unroll
            for (int nt = 0; nt < 2; nt++)
                #pragma unroll
                for (int i = 0; i < 16; i++) acc[mt][nt][i] = 0.f;

        for (int ks = 0; ks < 16; ks++) {
            int c0 = ks * 32;
            __syncthreads();
            // ---- stage A: 128 rows x 32 k, transpose+convert+pack ----
            {
                uint32_t pk[4][4];   // [m-offset][k-offset]
                #pragma unroll
                for (int i = 0; i < 4; i++) {
                    int k = a_kq * 4 + i;
                    float4 v = *(const float4*)(zA + (size_t)(c0 + k) * HW);
                    uint32_t H01 = pack2(v.x, v.y);
                    uint32_t H23 = pack2(v.z, v.w);
                    U32H2 h01; h01.u = H01; U32H2 h23; h23.u = H23;
                    uint32_t L01 = pack2(v.x - (float)h01.h.x, v.y - (float)h01.h.y);
                    uint32_t L23 = pack2(v.z - (float)h23.h.x, v.w - (float)h23.h.y);
                    pk[0][i] = __builtin_amdgcn_perm(L01, H01, 0x05040100u);
                    pk[1][i] = __builtin_amdgcn_perm(L01, H01, 0x07060302u);
                    pk[2][i] = __builtin_amdgcn_perm(L23, H23, 0x05040100u);
                    pk[3][i] = __builtin_amdgcn_perm(L23, H23, 0x07060302u);
                }
                int m0 = (tid & 31) * 4;
                #pragma unroll
                for (int r = 0; r < 4; r++) {
                    uint4 w = make_uint4(pk[r][0], pk[r][1], pk[r][2], pk[r][3]);
                    *(uint4*)&aP[(m0 + r) * ASTR + a_kq * 4] = w;
                }
            }
            // ---- stage B: 128 codes x 32 k, convert (separate hi/lo) ----
            {
                const float* cbB = cb + (size_t)(jt * 128) * E_DIM + c0 + b_kq * 4;
                #pragma unroll
                for (int r = 0; r < 4; r++) {
                    int jl = b_j0 + 32 * r;
                    float4 v = *(const float4*)(cbB + (size_t)jl * E_DIM);
                    uint32_t H01 = pack2(v.x, v.y);
                    uint32_t H23 = pack2(v.z, v.w);
                    U32H2 h01; h01.u = H01; U32H2 h23; h23.u = H23;
                    uint32_t L01 = pack2(v.x - (float)h01.h.x, v.y - (float)h01.h.y);
                    uint32_t L23 = pack2(v.z - (float)h23.h.x, v.w - (float)h23.h.y);
                    *(uint2*)&bH[jl * BSTR + b_kq * 4] = make_uint2(H01, H23);
                    *(uint2*)&bL[jl * BSTR + b_kq * 4] = make_uint2(L01, L23);
                }
            }
            __syncthreads();

            // ---- MFMA: 2 ksub x 2 mt x 2 nt x 3 passes ----
            #pragma unroll
            for (int ks2 = 0; ks2 < 2; ks2++) {
                int k0 = ks2 * 16 + lh * 8;     // element k within 0..31
                frag8 ah[2], al[2];
                #pragma unroll
                for (int mt = 0; mt < 2; mt++) {
                    const uint32_t* pa = &aP[(wm * 64 + mt * 32 + l31) * ASTR + k0];
                    uint4 q0 = *(const uint4*)pa;
                    uint4 q1 = *(const uint4*)(pa + 4);
                    FragU uh, ul;
                    uh.u[0] = __builtin_amdgcn_perm(q0.y, q0.x, 0x05040100u);
                    uh.u[1] = __builtin_amdgcn_perm(q0.w, q0.z, 0x05040100u);
                    uh.u[2] = __builtin_amdgcn_perm(q1.y, q1.x, 0x05040100u);
                    uh.u[3] = __builtin_amdgcn_perm(q1.w, q1.z, 0x05040100u);
                    ul.u[0] = __builtin_amdgcn_perm(q0.y, q0.x, 0x07060302u);
                    ul.u[1] = __builtin_amdgcn_perm(q0.w, q0.z, 0x07060302u);
                    ul.u[2] = __builtin_amdgcn_perm(q1.y, q1.x, 0x07060302u);
                    ul.u[3] = __builtin_amdgcn_perm(q1.w, q1.z, 0x07060302u);
                    ah[mt] = uh.f; al[mt] = ul.f;
                }
                frag8 bh[2], bl[2];
                #pragma unroll
                for (int nt = 0; nt < 2; nt++) {
                    int n = wg * 64 + nt * 32 + l31;
                    bh[nt] = *(const frag8*)&bH[n * BSTR + k0];
                    bl[nt] = *(const frag8*)&bL[n * BSTR + k0];
                }
                #pragma unroll
                for (int mt = 0; mt < 2; mt++)
                    #pragma unroll
                    for (int nt = 0; nt < 2; nt++) {
                        acc[mt][nt] = __builtin_amdgcn_mfma_f32_32x32x16_f16(
                            ah[mt], bh[nt], acc[mt][nt], 0, 0, 0);
                        acc[mt][nt] = __builtin_amdgcn_mfma_f32_32x32x16_f16(
                            ah[mt], bl[nt], acc[mt][nt], 0, 0, 0);
                        acc[mt][nt] = __builtin_amdgcn_mfma_f32_32x32x16_f16(
                            al[mt], bh[nt], acc[mt][nt], 0, 0, 0);
                    }
            }
        }

        // ---- epilogue: d = ||e||^2 - 2 z.e, fold into running argmin ----
        int jbase = jt * 128 + wg * 64;
        float cn0 = cn[jbase + l31];
        float cn1 = cn[jbase + 32 + l31];
        int j0i = jbase + l31, j1i = jbase + 32 + l31;
        #pragma unroll
        for (int mt = 0; mt < 2; mt++) {
            #pragma unroll
            for (int r = 0; r < 16; r++) {
                float d0 = cn0 - 2.f * acc[mt][0][r];
                float d1 = cn1 - 2.f * acc[mt][1][r];
                float v; int ix;
                if (d1 < d0) { v = d1; ix = j1i; } else { v = d0; ix = j0i; }
                #pragma unroll
                for (int m = 1; m <= 16; m <<= 1) {
                    float ov = __shfl_xor(v, m);
                    int   oi = __shfl_xor(ix, m);
                    if (ov < v || (ov == v && oi < ix)) { v = ov; ix = oi; }
                }
                if (l31 == r) {
                    int row = wm * 64 + mt * 32 + (r & 3) + 8 * (r >> 2) + 4 * lh;
                    if (v < bwv[wg][row] ||
                        (v == bwv[wg][row] && ix < bwi[wg][row])) {
                        bwv[wg][row] = v; bwi[wg][row] = ix;
                    }
                }
            }
        }
    }

    __syncthreads();
    if (tid < 128) {
        float v0 = bwv[0][tid], v1 = bwv[1][tid];
        int   i0 = bwi[0][tid], i1 = bwi[1][tid];
        int best = (v1 < v0 || (v1 == v0 && i1 < i0)) ? i1 : i0;
        idxout[n0 + tid] = best;
    }
}

// ---------------------------------------------------------------------------
// Kernel 4: gather z_q, straight-through output, per-block loss partials
__global__ void k_gather_loss(const float* __restrict__ z,
                              const float* __restrict__ ct,
                              const int* __restrict__ idx,
                              float* __restrict__ out,
                              float* __restrict__ pl) {
    int g = blockIdx.x * blockDim.x + threadIdx.x;
    int w4 = g & 1023;
    int bc = g >> 10;
    int c  = bc & 511;
    int b  = bc >> 9;
    int n4 = b * 1024 + w4;

    int4 iv = *(const int4*)(idx + (size_t)n4 * 4);
    const float* ctc = ct + (size_t)c * N_E;
    float4 zq;
    zq.x = ctc[iv.x]; zq.y = ctc[iv.y]; zq.z = ctc[iv.z]; zq.w = ctc[iv.w];
    float4 zv = *(const float4*)(z + (size_t)g * 4);

    float4 d;
    d.x = zq.x - zv.x; d.y = zq.y - zv.y; d.z = zq.z - zv.z; d.w = zq.w - zv.w;
    float4 o;
    o.x = zv.x + d.x; o.y = zv.y + d.y; o.z = zv.z + d.z; o.w = zv.w + d.w;
    *(float4*)(out + (size_t)g * 4) = o;

    float ls = d.x * d.x + d.y * d.y + d.z * d.z + d.w * d.w;
    #pragma unroll
    for (int m = 32; m >= 1; m >>= 1) ls += __shfl_xor(ls, m);

    __shared__ float wsum[4];
    int lane = threadIdx.x & 63, wid = threadIdx.x >> 6;
    if (lane == 0) wsum[wid] = ls;
    __syncthreads();
    if (threadIdx.x == 0)
        pl[blockIdx.x] = wsum[0] + wsum[1] + wsum[2] + wsum[3];

    if (c == 0) {
        float* ip = out + IDX_OFF + (size_t)n4 * 4;
        ip[0] = (float)iv.x; ip[1] = (float)iv.y;
        ip[2] = (float)iv.z; ip[3] = (float)iv.w;
    }
}

// ---------------------------------------------------------------------------
// Kernel 5: reduce 8192 partials -> loss
__global__ void k_final(const float* __restrict__ pl, float* __restrict__ out) {
    float s = 0.f;
    for (int i = threadIdx.x; i < 8192; i += 256) s += pl[i];
    #pragma unroll
    for (int m = 32; m >= 1; m >>= 1) s += __shfl_xor(s, m);
    __shared__ float wsum[4];
    int lane = threadIdx.x & 63, wid = threadIdx.x >> 6;
    if (lane == 0) wsum[wid] = s;
    __syncthreads();
    if (threadIdx.x == 0) {
        float tot = wsum[0] + wsum[1] + wsum[2] + wsum[3];
        out[LOSS_OFF] = 1.25f * tot / (float)ZQ_SIZE;
    }
}

// ---------------------------------------------------------------------------
extern "C" void kernel_launch(void* const* d_in, const int* in_sizes, int n_in,
                              void* d_out, int out_size, void* d_ws, size_t ws_size,
                              hipStream_t stream) {
    const float* z  = (const float*)d_in[0];
    const float* cb = (const float*)d_in[1];
    float* out = (float*)d_out;

    float* cn = (float*)d_ws + 16;          // byte offset 64
    float* ct = cn + 1024;                  // 512*1024 floats
    int*   idx = (int*)(ct + 512 * 1024);   // 65536 ints
    float* pl  = (float*)(idx + 65536);     // 8192 partials

    k_prep_norms<<<256, 256, 0, stream>>>(cb, cn);
    k_transpose<<<512, 256, 0, stream>>>(cb, ct);
    k_argmin_mfma<<<NROW / 128, 256, 0, stream>>>(z, cb, cn, idx);
    k_gather_loss<<<ZQ_SIZE / 4 / 256, 256, 0, stream>>>(z, ct, idx, out, pl);
    k_final<<<1, 256, 0, stream>>>(pl, out);
}

// Round 4
// 536.124 us; speedup vs baseline: 3.1069x; 1.1472x over previous
//
#include <hip/hip_runtime.h>

// Problem constants
#define N_E    1024
#define E_DIM  512
#define BATCH  16
#define HW     4096                       // 64*64
#define NROW   (BATCH * HW)               // 65536 vectors
#define ZQ_SIZE (BATCH * E_DIM * HW)      // 8388608
#define LOSS_OFF ZQ_SIZE
#define IDX_OFF (ZQ_SIZE + 1)

typedef _Float16 half_t;
typedef __attribute__((ext_vector_type(2)))  __fp16   fp16x2;  // cvt_pkrtz native type
typedef __attribute__((ext_vector_type(8)))  _Float16 frag8;   // 4 VGPR MFMA operand
typedef __attribute__((ext_vector_type(16))) float    accv;    // 16 AGPR accumulator

union U32H2 { fp16x2 h; uint32_t u; };
union FragU { uint32_t u[4]; frag8 f; };

static __device__ inline uint32_t pack2(float a, float b) {
    U32H2 t; t.h = __builtin_amdgcn_cvt_pkrtz(a, b); return t.u;
}

// ---------------------------------------------------------------------------
// Kernel 1 (fused prep): codebook transpose (all 512 blocks), code norms
// (blocks 0..255), best[] init to +inf key (first 65536 threads).
__global__ void k_prep(const float* __restrict__ cb,
                       float* __restrict__ cn,
                       float* __restrict__ ct,
                       unsigned long long* __restrict__ best) {
    __shared__ float t[32][33];
    int tx = threadIdx.x & 31;
    int ty = threadIdx.x >> 5;
    int jt = blockIdx.x & 31;
    int ctl = blockIdx.x >> 5;
    int j0 = jt * 32, c0 = ctl * 32;
    #pragma unroll
    for (int i = 0; i < 4; i++) {
        int row = ty + i * 8;
        t[row][tx] = cb[(size_t)(j0 + row) * E_DIM + c0 + tx];
    }
    __syncthreads();
    #pragma unroll
    for (int i = 0; i < 4; i++) {
        int row = ty + i * 8;
        ct[(size_t)(c0 + row) * N_E + j0 + tx] = t[tx][row];
    }

    if (blockIdx.x < 256) {
        int lane = threadIdx.x & 63;
        int wid  = threadIdx.x >> 6;
        int j = blockIdx.x * 4 + wid;
        const float* row = cb + (size_t)j * E_DIM;
        float s = 0.f;
        #pragma unroll
        for (int k = 0; k < E_DIM; k += 64) {
            float v = row[k + lane];
            s += v * v;
        }
        #pragma unroll
        for (int m = 32; m >= 1; m >>= 1) s += __shfl_xor(s, m);
        if (lane == 0) cn[j] = s;
    }

    int g = blockIdx.x * 256 + threadIdx.x;
    if (g < NROW) best[g] = 0xFFFFFFFFFFFFFFFFull;
}

// ---------------------------------------------------------------------------
// Kernel 2: MFMA distance argmin, j-split.
// Grid 4096 = 512 m-tiles x 8 j-tiles; block = 128 rows x 128 codes, K=512
// in 16 chunks of 32. f16-split (hi/lo) 3-pass MFMA. Cross-block combine via
// packed-u64 global atomicMin (mono-float-bits<<32 | index).
// A quads XOR-swizzled (q^=(row>>3)&7) at write+read: write conflicts 16-way
// -> floor, read stays at b128 floor.
#define ASTR 44   // dwords per A row (32 + pad; 176 B = 11 quads, odd -> good)
#define BSTR 40   // halves per B row (80 B = 5 quads, odd -> good)

__global__ __launch_bounds__(256, 2) void k_argmin_mfma(
        const float* __restrict__ z,
        const float* __restrict__ cb,
        const float* __restrict__ cn,
        unsigned long long* __restrict__ best) {
    __shared__ uint32_t aP[128 * ASTR];
    __shared__ half_t   bH[128 * BSTR];
    __shared__ half_t   bL[128 * BSTR];

    int tid  = threadIdx.x;
    int lane = tid & 63;
    int l31  = lane & 31;
    int lh   = lane >> 5;
    int wm   = (tid >> 6) & 1;   // wave m-group (rows)
    int wg   = tid >> 7;         // wave n-group (codes)

    int jt    = blockIdx.x & 7;          // 8 consecutive blocks share m-tile
    int mtile = blockIdx.x >> 3;
    int n0  = mtile * 128;
    int b   = n0 >> 12;
    int hw0 = n0 & 4095;
    const float* zA = z + (size_t)b * E_DIM * HW + hw0 + 4 * (tid & 31);
    int a_kq = tid >> 5;                      // 0..7 (k quad for A staging)
    int b_kq = tid & 7;                       // k quad for B staging
    int b_j0 = tid >> 3;                      // 0..31

    accv acc[2][2];
    #pragma unroll
    for (int mt = 0; mt < 2; mt++)
        #pragma unroll
        for (int nt = 0; nt < 2; nt++)
            #pragma unroll
            for (int i = 0; i < 16; i++) acc[mt][nt][i] = 0.f;

    for (int ks = 0; ks < 16; ks++) {
        int c0 = ks * 32;
        __syncthreads();
        // ---- stage A: 128 rows x 32 k, transpose+convert+pack, swizzled ----
        {
            uint32_t pk[4][4];   // [m-offset][k-offset]
            #pragma unroll
            for (int i = 0; i < 4; i++) {
                int k = a_kq * 4 + i;
                float4 v = *(const float4*)(zA + (size_t)(c0 + k) * HW);
                uint32_t H01 = pack2(v.x, v.y);
                uint32_t H23 = pack2(v.z, v.w);
                U32H2 h01; h01.u = H01; U32H2 h23; h23.u = H23;
                uint32_t L01 = pack2(v.x - (float)h01.h.x, v.y - (float)h01.h.y);
                uint32_t L23 = pack2(v.z - (float)h23.h.x, v.w - (float)h23.h.y);
                pk[0][i] = __builtin_amdgcn_perm(L01, H01, 0x05040100u);
                pk[1][i] = __builtin_amdgcn_perm(L01, H01, 0x07060302u);
                pk[2][i] = __builtin_amdgcn_perm(L23, H23, 0x05040100u);
                pk[3][i] = __builtin_amdgcn_perm(L23, H23, 0x07060302u);
            }
            int m0 = (tid & 31) * 4;
            #pragma unroll
            for (int r = 0; r < 4; r++) {
                int row = m0 + r;
                int qs = a_kq ^ ((row >> 3) & 7);
                uint4 w = make_uint4(pk[r][0], pk[r][1], pk[r][2], pk[r][3]);
                *(uint4*)&aP[row * ASTR + qs * 4] = w;
            }
        }
        // ---- stage B: 128 codes x 32 k, convert (separate hi/lo) ----
        {
            const float* cbB = cb + (size_t)(jt * 128) * E_DIM + c0 + b_kq * 4;
            #pragma unroll
            for (int r = 0; r < 4; r++) {
                int jl = b_j0 + 32 * r;
                float4 v = *(const float4*)(cbB + (size_t)jl * E_DIM);
                uint32_t H01 = pack2(v.x, v.y);
                uint32_t H23 = pack2(v.z, v.w);
                U32H2 h01; h01.u = H01; U32H2 h23; h23.u = H23;
                uint32_t L01 = pack2(v.x - (float)h01.h.x, v.y - (float)h01.h.y);
                uint32_t L23 = pack2(v.z - (float)h23.h.x, v.w - (float)h23.h.y);
                *(uint2*)&bH[jl * BSTR + b_kq * 4] = make_uint2(H01, H23);
                *(uint2*)&bL[jl * BSTR + b_kq * 4] = make_uint2(L01, L23);
            }
        }
        __syncthreads();

        // ---- MFMA: 2 ksub x 2 mt x 2 nt x 3 passes ----
        #pragma unroll
        for (int ks2 = 0; ks2 < 2; ks2++) {
            int k0 = ks2 * 16 + lh * 8;     // dword index within row (0,8,16,24)
            int q0 = k0 >> 2;               // quad index (0,2,4,6)
            frag8 ah[2], al[2];
            #pragma unroll
            for (int mt = 0; mt < 2; mt++) {
                int row = wm * 64 + mt * 32 + l31;
                int sw  = (row >> 3) & 7;
                const uint32_t* pr = &aP[row * ASTR];
                uint4 q0v = *(const uint4*)(pr + ((q0 ^ sw) << 2));
                uint4 q1v = *(const uint4*)(pr + (((q0 + 1) ^ sw) << 2));
                FragU uh, ul;
                uh.u[0] = __builtin_amdgcn_perm(q0v.y, q0v.x, 0x05040100u);
                uh.u[1] = __builtin_amdgcn_perm(q0v.w, q0v.z, 0x05040100u);
                uh.u[2] = __builtin_amdgcn_perm(q1v.y, q1v.x, 0x05040100u);
                uh.u[3] = __builtin_amdgcn_perm(q1v.w, q1v.z, 0x05040100u);
                ul.u[0] = __builtin_amdgcn_perm(q0v.y, q0v.x, 0x07060302u);
                ul.u[1] = __builtin_amdgcn_perm(q0v.w, q0v.z, 0x07060302u);
                ul.u[2] = __builtin_amdgcn_perm(q1v.y, q1v.x, 0x07060302u);
                ul.u[3] = __builtin_amdgcn_perm(q1v.w, q1v.z, 0x07060302u);
                ah[mt] = uh.f; al[mt] = ul.f;
            }
            frag8 bh[2], bl[2];
            #pragma unroll
            for (int nt = 0; nt < 2; nt++) {
                int n = wg * 64 + nt * 32 + l31;
                bh[nt] = *(const frag8*)&bH[n * BSTR + k0];
                bl[nt] = *(const frag8*)&bL[n * BSTR + k0];
            }
            #pragma unroll
            for (int mt = 0; mt < 2; mt++)
                #pragma unroll
                for (int nt = 0; nt < 2; nt++) {
                    acc[mt][nt] = __builtin_amdgcn_mfma_f32_32x32x16_f16(
                        ah[mt], bh[nt], acc[mt][nt], 0, 0, 0);
                    acc[mt][nt] = __builtin_amdgcn_mfma_f32_32x32x16_f16(
                        ah[mt], bl[nt], acc[mt][nt], 0, 0, 0);
                    acc[mt][nt] = __builtin_amdgcn_mfma_f32_32x32x16_f16(
                        al[mt], bh[nt], acc[mt][nt], 0, 0, 0);
                }
        }
    }

    // ---- epilogue: d = ||e||^2 - 2 z.e, butterfly per row, global atomicMin
    int jbase = jt * 128 + wg * 64;
    float cn0 = cn[jbase + l31];
    float cn1 = cn[jbase + 32 + l31];
    int j0i = jbase + l31, j1i = jbase + 32 + l31;
    #pragma unroll
    for (int mt = 0; mt < 2; mt++) {
        #pragma unroll
        for (int r = 0; r < 16; r++) {
            float d0 = cn0 - 2.f * acc[mt][0][r];
            float d1 = cn1 - 2.f * acc[mt][1][r];
            float v; int ix;
            if (d1 < d0) { v = d1; ix = j1i; } else { v = d0; ix = j0i; }
            #pragma unroll
            for (int m = 1; m <= 16; m <<= 1) {
                float ov = __shfl_xor(v, m);
                int   oi = __shfl_xor(ix, m);
                if (ov < v || (ov == v && oi < ix)) { v = ov; ix = oi; }
            }
            if (l31 == r) {
                int row = wm * 64 + mt * 32 + (r & 3) + 8 * (r >> 2) + 4 * lh;
                uint32_t s = __float_as_uint(v);
                uint32_t k32 = (s & 0x80000000u) ? ~s : (s | 0x80000000u);
                unsigned long long key =
                    ((unsigned long long)k32 << 32) | (uint32_t)ix;
                atomicMin(&best[n0 + row], key);
            }
        }
    }
}

// ---------------------------------------------------------------------------
// Kernel 3: gather z_q, straight-through output, per-block loss partials.
// Index comes from low 32 bits of best[] (L2-resident, broadcast across c).
__global__ void k_gather_loss(const float* __restrict__ z,
                              const float* __restrict__ ct,
                              const unsigned long long* __restrict__ best,
                              float* __restrict__ out,
                              float* __restrict__ pl) {
    int g = blockIdx.x * blockDim.x + threadIdx.x;
    int w4 = g & 1023;
    int bc = g >> 10;
    int c  = bc & 511;
    int b  = bc >> 9;
    int n4 = b * 1024 + w4;

    ulonglong2 b01 = *(const ulonglong2*)(best + (size_t)n4 * 4);
    ulonglong2 b23 = *(const ulonglong2*)(best + (size_t)n4 * 4 + 2);
    int4 iv;
    iv.x = (int)(uint32_t)b01.x; iv.y = (int)(uint32_t)b01.y;
    iv.z = (int)(uint32_t)b23.x; iv.w = (int)(uint32_t)b23.y;

    const float* ctc = ct + (size_t)c * N_E;
    float4 zq;
    zq.x = ctc[iv.x]; zq.y = ctc[iv.y]; zq.z = ctc[iv.z]; zq.w = ctc[iv.w];
    float4 zv = *(const float4*)(z + (size_t)g * 4);

    float4 d;
    d.x = zq.x - zv.x; d.y = zq.y - zv.y; d.z = zq.z - zv.z; d.w = zq.w - zv.w;
    float4 o;
    o.x = zv.x + d.x; o.y = zv.y + d.y; o.z = zv.z + d.z; o.w = zv.w + d.w;
    *(float4*)(out + (size_t)g * 4) = o;

    float ls = d.x * d.x + d.y * d.y + d.z * d.z + d.w * d.w;
    #pragma unroll
    for (int m = 32; m >= 1; m >>= 1) ls += __shfl_xor(ls, m);

    __shared__ float wsum[4];
    int lane = threadIdx.x & 63, wid = threadIdx.x >> 6;
    if (lane == 0) wsum[wid] = ls;
    __syncthreads();
    if (threadIdx.x == 0)
        pl[blockIdx.x] = wsum[0] + wsum[1] + wsum[2] + wsum[3];

    if (c == 0) {
        float* ip = out + IDX_OFF + (size_t)n4 * 4;
        ip[0] = (float)iv.x; ip[1] = (float)iv.y;
        ip[2] = (float)iv.z; ip[3] = (float)iv.w;
    }
}

// ---------------------------------------------------------------------------
// Kernel 4: reduce 8192 partials -> loss
__global__ void k_final(const float* __restrict__ pl, float* __restrict__ out) {
    float s = 0.f;
    for (int i = threadIdx.x; i < 8192; i += 256) s += pl[i];
    #pragma unroll
    for (int m = 32; m >= 1; m >>= 1) s += __shfl_xor(s, m);
    __shared__ float wsum[4];
    int lane = threadIdx.x & 63, wid = threadIdx.x >> 6;
    if (lane == 0) wsum[wid] = s;
    __syncthreads();
    if (threadIdx.x == 0) {
        float tot = wsum[0] + wsum[1] + wsum[2] + wsum[3];
        out[LOSS_OFF] = 1.25f * tot / (float)ZQ_SIZE;
    }
}

// ---------------------------------------------------------------------------
extern "C" void kernel_launch(void* const* d_in, const int* in_sizes, int n_in,
                              void* d_out, int out_size, void* d_ws, size_t ws_size,
                              hipStream_t stream) {
    const float* z  = (const float*)d_in[0];
    const float* cb = (const float*)d_in[1];
    float* out = (float*)d_out;

    float* cn = (float*)d_ws + 16;                       // byte offset 64
    float* ct = cn + 1024;                               // 512*1024 floats
    unsigned long long* best =
        (unsigned long long*)(ct + 512 * 1024);          // 65536 u64
    float* pl = (float*)(best + NROW);                   // 8192 partials

    k_prep<<<512, 256, 0, stream>>>(cb, cn, ct, best);
    k_argmin_mfma<<<4096, 256, 0, stream>>>(z, cb, cn, best);
    k_gather_loss<<<ZQ_SIZE / 4 / 256, 256, 0, stream>>>(z, ct, best, out, pl);
    k_final<<<1, 256, 0, stream>>>(pl, out);
}